// Round 3
// baseline (6866.930 us; speedup 1.0000x reference)
//
#include <hip/hip_runtime.h>

// LSTM: T=512, B=64, I=512, H=512, gates 4H=2048.
// ALL inputs fp32 (per reference setup_inputs), OUTPUT fp32.
// MFMA path uses on-the-fly bf16 conversion (weights converted once into LDS).
// One persistent kernel, 64 blocks x 256 threads (4 waves).
// Block b owns h-columns [8b, 8b+8) -> gate columns {q*512 + 8b + j}.
// Recurrent h kept as bf16 in a ws double-buffer; out gets fp32 h.
// Cross-block sync via per-step flags in d_ws.

#define T_STEPS 512
#define BATCH   64
#define HID     512
#define NB      64

typedef short bf16x8 __attribute__((ext_vector_type(8)));
typedef float f32x4  __attribute__((ext_vector_type(4)));

__device__ __forceinline__ unsigned short f2bf(float f) {
    unsigned int u = __builtin_bit_cast(unsigned int, f);
    u += 0x7FFFu + ((u >> 16) & 1u);
    return (unsigned short)(u >> 16);
}
__device__ __forceinline__ unsigned int pack2(float lo, float hi) {
    return (unsigned int)f2bf(lo) | ((unsigned int)f2bf(hi) << 16);
}
// load 8 consecutive fp32 from p, round to bf16, pack into 16 B
__device__ __forceinline__ uint4 cvt8(const float* __restrict__ p) {
    float4 f0 = *(const float4*)p;
    float4 f1 = *(const float4*)(p + 4);
    uint4 r;
    r.x = pack2(f0.x, f0.y);
    r.y = pack2(f0.z, f0.w);
    r.z = pack2(f1.x, f1.y);
    r.w = pack2(f1.z, f1.w);
    return r;
}
__device__ __forceinline__ float sigmoidf_(float x) {
    return 1.0f / (1.0f + __expf(-x));
}
__device__ __forceinline__ float tanhf_(float x) {
    x = fminf(fmaxf(x, -15.f), 15.f);
    float e = __expf(2.0f * x);
    return (e - 1.0f) / (e + 1.0f);
}

extern "C" __global__ void __launch_bounds__(256, 1)
lstm_fused(const float* __restrict__ x,
           const float* __restrict__ W_ih,
           const float* __restrict__ W_hh,
           const float* __restrict__ b_ih,
           const float* __restrict__ b_hh,
           float* __restrict__ out,
           unsigned int* __restrict__ flags,
           unsigned short* __restrict__ hbuf)   // 2 buffers of [BATCH][HID] bf16
{
    // [matrix 0=W_ih,1=W_hh][ntile][kk][lane] : 16B per lane = MFMA B-fragment
    __shared__ uint4 sB[2][2][16][64];

    const int blk  = blockIdx.x;
    const int tid  = threadIdx.x;
    const int w    = tid >> 6;    // wave id 0..3 -> M-tile (batch rows 16w..16w+15)
    const int lane = tid & 63;
    const int l15  = lane & 15;
    const int quad = lane >> 4;
    const int hc0  = blk * 8;     // first owned h-column

    // ---- one-time: stage W slices into LDS in B-fragment order (fp32 -> bf16) ----
    // B-frag for ntile nt, k-chunk kk: lane holds W[gcol(l15+16*nt)][kk*32+quad*8 .. +7]
    for (int u = tid; u < 2 * 16 * 64; u += 256) {
        int nt   = u >> 10;
        int kk   = (u >> 6) & 15;
        int ln   = u & 63;
        int c    = (ln & 15) + (nt << 4);                 // local gate col 0..31
        int grow = ((c >> 3) << 9) + hc0 + (c & 7);       // global W row (gate*512 + hcol)
        int k0   = kk * 32 + ((ln >> 4) << 3);
        sB[0][nt][kk][ln] = cvt8(W_ih + grow * 512 + k0);
        sB[1][nt][kk][ln] = cvt8(W_hh + grow * 512 + k0);
    }

    // per-lane biases for its two gate columns (fp32)
    float bias0, bias1;
    {
        int c0 = l15,      g0 = ((c0 >> 3) << 9) + hc0 + (c0 & 7);
        int c1 = l15 + 16, g1 = ((c1 >> 3) << 9) + hc0 + (c1 & 7);
        bias0 = b_ih[g0] + b_hh[g0];
        bias1 = b_ih[g1] + b_hh[g1];
    }
    __syncthreads();

    float cst[4] = {0.f, 0.f, 0.f, 0.f};     // c-state: 4 rows of owned column (lanes l15<8)
    const int aoff = (((w << 4) + l15) * 512) + (quad << 3);  // A-fragment lane offset
    long long budget = 50000000LL;            // deadlock safety valve

    for (int t = 0; t < T_STEPS; ++t) {
        f32x4 acc0 = {0.f, 0.f, 0.f, 0.f};
        f32x4 acc1 = {0.f, 0.f, 0.f, 0.f};

        // ---- x-projection part (no cross-block dependency; hides flag wait) ----
        const float* xt = x + (size_t)t * (BATCH * 512) + aoff;
#pragma unroll
        for (int kk = 0; kk < 16; ++kk) {
            bf16x8 a  = __builtin_bit_cast(bf16x8, cvt8(xt + kk * 32));
            bf16x8 b0 = __builtin_bit_cast(bf16x8, sB[0][0][kk][lane]);
            bf16x8 b1 = __builtin_bit_cast(bf16x8, sB[0][1][kk][lane]);
            acc0 = __builtin_amdgcn_mfma_f32_16x16x32_bf16(a, b0, acc0, 0, 0, 0);
            acc1 = __builtin_amdgcn_mfma_f32_16x16x32_bf16(a, b1, acc1, 0, 0, 0);
        }

        // ---- recurrent part: wait for all h_{t-1} slices, then accumulate ----
        if (t > 0) {
            if (w == 0) {
                const unsigned int* fp = flags + (size_t)(t - 1) * NB + lane;
                while (budget > 0) {
                    unsigned int v = __hip_atomic_load(fp, __ATOMIC_RELAXED,
                                                       __HIP_MEMORY_SCOPE_AGENT);
                    if (__all(v != 0)) break;
                    --budget;
                }
            }
            __syncthreads();
            __builtin_amdgcn_fence(__ATOMIC_ACQUIRE, "agent");

            const unsigned short* hp = hbuf + (size_t)((t - 1) & 1) * (BATCH * HID) + aoff;
#pragma unroll
            for (int kk = 0; kk < 16; ++kk) {
                bf16x8 a  = *(const bf16x8*)(hp + kk * 32);
                bf16x8 b0 = __builtin_bit_cast(bf16x8, sB[1][0][kk][lane]);
                bf16x8 b1 = __builtin_bit_cast(bf16x8, sB[1][1][kk][lane]);
                acc0 = __builtin_amdgcn_mfma_f32_16x16x32_bf16(a, b0, acc0, 0, 0, 0);
                acc1 = __builtin_amdgcn_mfma_f32_16x16x32_bf16(a, b1, acc1, 0, 0, 0);
            }
        }

        // ---- gates + state update ----
        // C-layout: col = lane&15, row = quad*4 + reg.
        // acc0 col c=l15      : gate i (l15<8) / f (l15>=8), h-col = hc0 + (l15&7)
        // acc1 col c=l15+16   : gate g (l15<8) / o (l15>=8)
        float gi[4], gf[4], gg[4], go[4];
#pragma unroll
        for (int r = 0; r < 4; ++r) {
            float a0 = acc0[r] + bias0;
            float a1 = acc1[r] + bias1;
            float p0 = __shfl_xor(a0, 8, 64);
            float p1 = __shfl_xor(a1, 8, 64);
            gi[r] = a0; gg[r] = a1; gf[r] = p0; go[r] = p1;
        }
        if (l15 < 8) {
            const int rbase = (w << 4) + (quad << 2);
            float*          op = out  + (size_t)t * (BATCH * HID) + hc0 + l15;
            unsigned short* hb = hbuf + (size_t)(t & 1) * (BATCH * HID) + hc0 + l15;
#pragma unroll
            for (int r = 0; r < 4; ++r) {
                float iv = sigmoidf_(gi[r]);
                float fv = sigmoidf_(gf[r]);
                float gv = tanhf_(gg[r]);
                float ov = sigmoidf_(go[r]);
                cst[r] = fv * cst[r] + iv * gv;
                float hv = ov * tanhf_(cst[r]);
                op[(size_t)(rbase + r) * HID] = hv;         // fp32 output
                hb[(size_t)(rbase + r) * HID] = f2bf(hv);   // bf16 recurrent state
            }
        }

        // ---- publish h_t ----
        __syncthreads();   // all waves' stores drained (vmcnt(0) before barrier)
        __builtin_amdgcn_fence(__ATOMIC_RELEASE, "agent");  // write back XCD-local L2
        if (tid == 0) {
            __hip_atomic_store(flags + (size_t)t * NB + blk, 1u,
                               __ATOMIC_RELEASE, __HIP_MEMORY_SCOPE_AGENT);
        }
    }
}

extern "C" void kernel_launch(void* const* d_in, const int* in_sizes, int n_in,
                              void* d_out, int out_size, void* d_ws, size_t ws_size,
                              hipStream_t stream) {
    const float* x    = (const float*)d_in[0];
    const float* W_ih = (const float*)d_in[1];
    const float* W_hh = (const float*)d_in[2];
    const float* b_ih = (const float*)d_in[3];
    const float* b_hh = (const float*)d_in[4];
    float* out = (float*)d_out;

    unsigned int*   flags = (unsigned int*)d_ws;
    const size_t    flag_bytes = (size_t)T_STEPS * NB * sizeof(unsigned int);  // 128 KB
    unsigned short* hbuf  = (unsigned short*)((char*)d_ws + flag_bytes);        // 2x64 KB

    // flags re-zeroed every call (ws is re-poisoned to 0xAA by the harness)
    hipMemsetAsync(flags, 0, flag_bytes, stream);

    hipLaunchKernelGGL(lstm_fused, dim3(NB), dim3(256), 0, stream,
                       x, W_ih, W_hh, b_ih, b_hh, out, flags, hbuf);
}

// Round 4
// 4892.829 us; speedup vs baseline: 1.4035x; 1.4035x over previous
//
#include <hip/hip_runtime.h>

// LSTM: T=512, B=64, I=512, H=512, gates 4H=2048. Inputs fp32, output fp32.
// One persistent kernel, 64 blocks x 256 threads (4 waves).
// Block b owns h-columns [8b, 8b+8) -> gate columns {q*512 + 8b + j}.
// W slices in LDS pre-swizzled (bf16) into MFMA B-fragment order.
// Recurrent h kept bf16 in a ws double-buffer.
// Cross-block sync: per-step per-block flags + FINE-GRAINED coherent accesses
// (sc0/sc1 per-access via __hip_atomic_*) — NO agent fences (no whole-L2
// buffer_inv/buffer_wbl2 on the critical path).

#define T_STEPS 512
#define BATCH   64
#define HID     512
#define NB      64

typedef short bf16x8 __attribute__((ext_vector_type(8)));
typedef float f32x4  __attribute__((ext_vector_type(4)));

struct U16B { unsigned long long x, y; };

__device__ __forceinline__ unsigned short f2bf(float f) {
    unsigned int u = __builtin_bit_cast(unsigned int, f);
    u += 0x7FFFu + ((u >> 16) & 1u);
    return (unsigned short)(u >> 16);
}
__device__ __forceinline__ unsigned int pack2(float lo, float hi) {
    return (unsigned int)f2bf(lo) | ((unsigned int)f2bf(hi) << 16);
}
// load 8 consecutive fp32 from p, round to bf16, pack into 16 B
__device__ __forceinline__ uint4 cvt8(const float* __restrict__ p) {
    float4 f0 = *(const float4*)p;
    float4 f1 = *(const float4*)(p + 4);
    uint4 r;
    r.x = pack2(f0.x, f0.y);
    r.y = pack2(f0.z, f0.w);
    r.z = pack2(f1.x, f1.y);
    r.w = pack2(f1.z, f1.w);
    return r;
}
// coherent (L2-bypassing) 16-byte h-fragment load as 2x8B relaxed agent atomics
__device__ __forceinline__ bf16x8 load_h16(const unsigned short* p) {
    const unsigned long long* q = (const unsigned long long*)p;
    U16B v;
    v.x = __hip_atomic_load(q,     __ATOMIC_RELAXED, __HIP_MEMORY_SCOPE_AGENT);
    v.y = __hip_atomic_load(q + 1, __ATOMIC_RELAXED, __HIP_MEMORY_SCOPE_AGENT);
    return __builtin_bit_cast(bf16x8, v);
}
__device__ __forceinline__ float sigmoidf_(float x) {
    return 1.0f / (1.0f + __expf(-x));
}
__device__ __forceinline__ float tanhf_(float x) {
    x = fminf(fmaxf(x, -15.f), 15.f);
    float e = __expf(2.0f * x);
    return (e - 1.0f) / (e + 1.0f);
}

extern "C" __global__ void __launch_bounds__(256, 1)
lstm_fused(const float* __restrict__ x,
           const float* __restrict__ W_ih,
           const float* __restrict__ W_hh,
           const float* __restrict__ b_ih,
           const float* __restrict__ b_hh,
           float* __restrict__ out,
           unsigned int* __restrict__ flags,
           unsigned short* __restrict__ hbuf)   // 2 buffers of [BATCH][HID] bf16
{
    // [matrix 0=W_ih,1=W_hh][ntile][kk][lane] : 16B per lane = MFMA B-fragment
    __shared__ uint4 sB[2][2][16][64];

    const int blk  = blockIdx.x;
    const int tid  = threadIdx.x;
    const int w    = tid >> 6;    // wave id 0..3 -> M-tile (batch rows 16w..16w+15)
    const int lane = tid & 63;
    const int l15  = lane & 15;
    const int quad = lane >> 4;
    const int hc0  = blk * 8;     // first owned h-column

    // ---- one-time: stage W slices into LDS in B-fragment order (fp32 -> bf16) ----
    for (int u = tid; u < 2 * 16 * 64; u += 256) {
        int nt   = u >> 10;
        int kk   = (u >> 6) & 15;
        int ln   = u & 63;
        int c    = (ln & 15) + (nt << 4);                 // local gate col 0..31
        int grow = ((c >> 3) << 9) + hc0 + (c & 7);       // global W row (gate*512 + hcol)
        int k0   = kk * 32 + ((ln >> 4) << 3);
        sB[0][nt][kk][ln] = cvt8(W_ih + grow * 512 + k0);
        sB[1][nt][kk][ln] = cvt8(W_hh + grow * 512 + k0);
    }

    // per-lane biases for its two gate columns (fp32)
    float bias0, bias1;
    {
        int c0 = l15,      g0 = ((c0 >> 3) << 9) + hc0 + (c0 & 7);
        int c1 = l15 + 16, g1 = ((c1 >> 3) << 9) + hc0 + (c1 & 7);
        bias0 = b_ih[g0] + b_hh[g0];
        bias1 = b_ih[g1] + b_hh[g1];
    }
    __syncthreads();

    float cst[4] = {0.f, 0.f, 0.f, 0.f};     // c-state: 4 rows of owned column (lanes l15<8)
    const int aoff = (((w << 4) + l15) * 512) + (quad << 3);  // A-fragment lane offset
    long long budget = 200000000LL;           // deadlock safety valve

    for (int t = 0; t < T_STEPS; ++t) {
        f32x4 acc0 = {0.f, 0.f, 0.f, 0.f};
        f32x4 acc1 = {0.f, 0.f, 0.f, 0.f};

        // ---- x-projection part (no cross-block dependency; hides flag wait) ----
        const float* xt = x + (size_t)t * (BATCH * 512) + aoff;
#pragma unroll
        for (int kk = 0; kk < 16; ++kk) {
            bf16x8 a  = __builtin_bit_cast(bf16x8, cvt8(xt + kk * 32));
            bf16x8 b0 = __builtin_bit_cast(bf16x8, sB[0][0][kk][lane]);
            bf16x8 b1 = __builtin_bit_cast(bf16x8, sB[0][1][kk][lane]);
            acc0 = __builtin_amdgcn_mfma_f32_16x16x32_bf16(a, b0, acc0, 0, 0, 0);
            acc1 = __builtin_amdgcn_mfma_f32_16x16x32_bf16(a, b1, acc1, 0, 0, 0);
        }

        // ---- recurrent part: wait for all h_{t-1} slices, then accumulate ----
        if (t > 0) {
            if (w == 0) {
                const unsigned int* fp = flags + (size_t)(t - 1) * NB + lane;
                while (budget > 0) {
                    unsigned int v = __hip_atomic_load(fp, __ATOMIC_RELAXED,
                                                       __HIP_MEMORY_SCOPE_AGENT);
                    if (__all(v != 0)) break;
                    --budget;
                }
            }
            __syncthreads();   // acquire: flag loads already bypass L1/L2 (sc0 sc1)

            const unsigned short* hp = hbuf + (size_t)((t - 1) & 1) * (BATCH * HID) + aoff;
#pragma unroll
            for (int kk = 0; kk < 16; ++kk) {
                bf16x8 a  = load_h16(hp + kk * 32);   // coherent L2-bypass load
                bf16x8 b0 = __builtin_bit_cast(bf16x8, sB[1][0][kk][lane]);
                bf16x8 b1 = __builtin_bit_cast(bf16x8, sB[1][1][kk][lane]);
                acc0 = __builtin_amdgcn_mfma_f32_16x16x32_bf16(a, b0, acc0, 0, 0, 0);
                acc1 = __builtin_amdgcn_mfma_f32_16x16x32_bf16(a, b1, acc1, 0, 0, 0);
            }
        }

        // ---- gates + state update ----
        // C-layout: col = lane&15, row = quad*4 + reg.
        // acc0 col c=l15      : gate i (l15<8) / f (l15>=8), h-col = hc0 + (l15&7)
        // acc1 col c=l15+16   : gate g (l15<8) / o (l15>=8)
        float gi[4], gf[4], gg[4], go[4];
#pragma unroll
        for (int r = 0; r < 4; ++r) {
            float a0 = acc0[r] + bias0;
            float a1 = acc1[r] + bias1;
            float p0 = __shfl_xor(a0, 8, 64);
            float p1 = __shfl_xor(a1, 8, 64);
            gi[r] = a0; gg[r] = a1; gf[r] = p0; go[r] = p1;
        }
        if (l15 < 8) {
            const int rbase = (w << 4) + (quad << 2);
            float*          op = out  + (size_t)t * (BATCH * HID) + hc0 + l15;
            unsigned short* hb = hbuf + (size_t)(t & 1) * (BATCH * HID) + hc0 + l15;
#pragma unroll
            for (int r = 0; r < 4; ++r) {
                float iv = sigmoidf_(gi[r]);
                float fv = sigmoidf_(gf[r]);
                float gv = tanhf_(gg[r]);
                float ov = sigmoidf_(go[r]);
                cst[r] = fv * cst[r] + iv * gv;
                float hv = ov * tanhf_(cst[r]);
                op[(size_t)(rbase + r) * HID] = hv;         // fp32 output (cached)
                // write-through coherent bf16 recurrent state (sc0 sc1, no L2 dirty)
                __hip_atomic_store(hb + (size_t)(rbase + r) * HID, f2bf(hv),
                                   __ATOMIC_RELAXED, __HIP_MEMORY_SCOPE_AGENT);
            }
        }

        // ---- publish h_t ----
        // __syncthreads drains vmcnt(0): write-through h stores are acked at the
        // coherence point before any lane proceeds -> manual release, no wbl2.
        __syncthreads();
        if (tid == 0) {
            __hip_atomic_store(flags + (size_t)t * NB + blk, 1u,
                               __ATOMIC_RELAXED, __HIP_MEMORY_SCOPE_AGENT);
        }
    }
}

extern "C" void kernel_launch(void* const* d_in, const int* in_sizes, int n_in,
                              void* d_out, int out_size, void* d_ws, size_t ws_size,
                              hipStream_t stream) {
    const float* x    = (const float*)d_in[0];
    const float* W_ih = (const float*)d_in[1];
    const float* W_hh = (const float*)d_in[2];
    const float* b_ih = (const float*)d_in[3];
    const float* b_hh = (const float*)d_in[4];
    float* out = (float*)d_out;

    unsigned int*   flags = (unsigned int*)d_ws;
    const size_t    flag_bytes = (size_t)T_STEPS * NB * sizeof(unsigned int);  // 128 KB
    unsigned short* hbuf  = (unsigned short*)((char*)d_ws + flag_bytes);        // 2x64 KB

    // flags re-zeroed every call (ws is re-poisoned to 0xAA by the harness)
    hipMemsetAsync(flags, 0, flag_bytes, stream);

    hipLaunchKernelGGL(lstm_fused, dim3(NB), dim3(256), 0, stream,
                       x, W_ih, W_hh, b_ih, b_hh, out, flags, hbuf);
}

// Round 6
// 4320.795 us; speedup vs baseline: 1.5893x; 1.1324x over previous
//
#include <hip/hip_runtime.h>

// LSTM: T=512, B=64, I=512, H=512, gates 4H=2048. Inputs fp32, output fp32.
// One persistent kernel, 64 blocks x 256 threads (4 waves).
// Block b owns h-columns [8b, 8b+8) -> gate columns {q*512 + 8b + j}.
// W slices in LDS pre-swizzled (bf16) into MFMA B-fragment order.
// h published per-step as a COMPACT 1 KB/producer slice: [buf][p][row][8cols],
// stored with coherent write-through 8B atomic stores, read with coherent
// 8B atomic loads. Per-step per-block flags; no agent fences anywhere.

#define T_STEPS 512
#define BATCH   64
#define HID     512
#define NB      64

typedef short bf16x8 __attribute__((ext_vector_type(8)));
typedef float f32x4  __attribute__((ext_vector_type(4)));

struct U16B { unsigned long long x, y; };

__device__ __forceinline__ unsigned short f2bf(float f) {
    unsigned int u = __builtin_bit_cast(unsigned int, f);
    u += 0x7FFFu + ((u >> 16) & 1u);
    return (unsigned short)(u >> 16);
}
__device__ __forceinline__ unsigned int pack2(float lo, float hi) {
    return (unsigned int)f2bf(lo) | ((unsigned int)f2bf(hi) << 16);
}
// load 8 consecutive fp32 from p, round to bf16, pack into 16 B
__device__ __forceinline__ uint4 cvt8(const float* __restrict__ p) {
    float4 f0 = *(const float4*)p;
    float4 f1 = *(const float4*)(p + 4);
    uint4 r;
    r.x = pack2(f0.x, f0.y);
    r.y = pack2(f0.z, f0.w);
    r.z = pack2(f1.x, f1.y);
    r.w = pack2(f1.z, f1.w);
    return r;
}
// coherent (L2-bypassing) 16-byte h-fragment load as 2x8B relaxed agent atomics
__device__ __forceinline__ bf16x8 load_h16(const void* p) {
    const unsigned long long* q = (const unsigned long long*)p;
    U16B v;
    v.x = __hip_atomic_load(q,     __ATOMIC_RELAXED, __HIP_MEMORY_SCOPE_AGENT);
    v.y = __hip_atomic_load(q + 1, __ATOMIC_RELAXED, __HIP_MEMORY_SCOPE_AGENT);
    return __builtin_bit_cast(bf16x8, v);
}
// coherent write-through 16-byte store as 2x8B relaxed agent atomics
__device__ __forceinline__ void store_cg16(void* p, uint4 v) {
    unsigned long long* q = (unsigned long long*)p;
    U16B u = __builtin_bit_cast(U16B, v);
    __hip_atomic_store(q,     u.x, __ATOMIC_RELAXED, __HIP_MEMORY_SCOPE_AGENT);
    __hip_atomic_store(q + 1, u.y, __ATOMIC_RELAXED, __HIP_MEMORY_SCOPE_AGENT);
}
__device__ __forceinline__ float sigmoidf_(float x) {
    return 1.0f / (1.0f + __expf(-x));
}
__device__ __forceinline__ float tanhf_(float x) {
    x = fminf(fmaxf(x, -15.f), 15.f);
    float e = __expf(2.0f * x);
    return (e - 1.0f) / (e + 1.0f);
}

extern "C" __global__ void __launch_bounds__(256, 1)
lstm_fused(const float* __restrict__ x,
           const float* __restrict__ W_ih,
           const float* __restrict__ W_hh,
           const float* __restrict__ b_ih,
           const float* __restrict__ b_hh,
           float* __restrict__ out,
           unsigned int* __restrict__ flags,
           unsigned short* __restrict__ hbuf)  // [2][NB][64 rows][8 cols] bf16 = 128 KB
{
    // [matrix 0=W_ih,1=W_hh][ntile][kk][lane] : 16B per lane = MFMA B-fragment
    __shared__ uint4 sB[2][2][16][64];
    // per-wave h transpose patch: [wave][row-in-tile][8 cols]
    __shared__ __align__(16) unsigned short sH[4][16][8];

    const int blk  = blockIdx.x;
    const int tid  = threadIdx.x;
    const int w    = tid >> 6;    // wave id 0..3 -> M-tile (batch rows 16w..16w+15)
    const int lane = tid & 63;
    const int l15  = lane & 15;
    const int quad = lane >> 4;
    const int hc0  = blk * 8;     // first owned h-column

    // ---- one-time: stage W slices into LDS in B-fragment order (fp32 -> bf16) ----
    for (int u = tid; u < 2 * 16 * 64; u += 256) {
        int nt   = u >> 10;
        int kk   = (u >> 6) & 15;
        int ln   = u & 63;
        int c    = (ln & 15) + (nt << 4);                 // local gate col 0..31
        int grow = ((c >> 3) << 9) + hc0 + (c & 7);       // global W row (gate*512 + hcol)
        int k0   = kk * 32 + ((ln >> 4) << 3);
        sB[0][nt][kk][ln] = cvt8(W_ih + grow * 512 + k0);
        sB[1][nt][kk][ln] = cvt8(W_hh + grow * 512 + k0);
    }

    // per-lane biases for its two gate columns (fp32)
    float bias0, bias1;
    {
        int c0 = l15,      g0 = ((c0 >> 3) << 9) + hc0 + (c0 & 7);
        int c1 = l15 + 16, g1 = ((c1 >> 3) << 9) + hc0 + (c1 & 7);
        bias0 = b_ih[g0] + b_hh[g0];
        bias1 = b_ih[g1] + b_hh[g1];
    }
    __syncthreads();

    float cst[4] = {0.f, 0.f, 0.f, 0.f};     // c-state: 4 rows of owned column (lanes l15<8)
    const int aoff = (((w << 4) + l15) * 512) + (quad << 3);  // x A-fragment lane offset
    // consumer h-read base (row = 16w+l15, producer varies per chunk/quad)
    char* const hb_base = (char*)hbuf;
    const int   hread_off = (quad << 10) + (((w << 4) + l15) << 4);  // p=quad part + row*16
    long long budget = 50000000LL;            // deadlock safety valve

    for (int t = 0; t < T_STEPS; ++t) {
        f32x4 acc0 = {0.f, 0.f, 0.f, 0.f};
        f32x4 acc1 = {0.f, 0.f, 0.f, 0.f};

        // ---- x-projection part (no cross-block dependency; hides flag wait) ----
        const float* xt = x + (size_t)t * (BATCH * 512) + aoff;
#pragma unroll
        for (int kk = 0; kk < 16; ++kk) {
            bf16x8 a  = __builtin_bit_cast(bf16x8, cvt8(xt + kk * 32));
            bf16x8 b0 = __builtin_bit_cast(bf16x8, sB[0][0][kk][lane]);
            bf16x8 b1 = __builtin_bit_cast(bf16x8, sB[0][1][kk][lane]);
            acc0 = __builtin_amdgcn_mfma_f32_16x16x32_bf16(a, b0, acc0, 0, 0, 0);
            acc1 = __builtin_amdgcn_mfma_f32_16x16x32_bf16(a, b1, acc1, 0, 0, 0);
        }

        // ---- recurrent part: wait for all h_{t-1} slices, then accumulate ----
        if (t > 0) {
            if (w == 0) {
                const unsigned int* fp = flags + (size_t)(t - 1) * NB + lane;
                while (budget > 0) {
                    unsigned int v = __hip_atomic_load(fp, __ATOMIC_RELAXED,
                                                       __HIP_MEMORY_SCOPE_AGENT);
                    if (__all(v != 0)) break;
                    --budget;
                }
            }
            __syncthreads();   // acquire: flag loads bypass L1/L2 (sc0 sc1)

            // chunk kk, quad q -> producer p = 4kk+q, 16 contiguous bytes at row
            const char* hp = hb_base + (((t - 1) & 1) << 16) + hread_off;
#pragma unroll
            for (int kk = 0; kk < 16; ++kk) {
                bf16x8 a  = load_h16(hp + (kk << 12));   // coherent L2-bypass load
                bf16x8 b0 = __builtin_bit_cast(bf16x8, sB[1][0][kk][lane]);
                bf16x8 b1 = __builtin_bit_cast(bf16x8, sB[1][1][kk][lane]);
                acc0 = __builtin_amdgcn_mfma_f32_16x16x32_bf16(a, b0, acc0, 0, 0, 0);
                acc1 = __builtin_amdgcn_mfma_f32_16x16x32_bf16(a, b1, acc1, 0, 0, 0);
            }
        }

        // ---- gates + state update ----
        // C-layout: col = lane&15, row = quad*4 + reg.
        // acc0 col c=l15      : gate i (l15<8) / f (l15>=8), h-col = hc0 + (l15&7)
        // acc1 col c=l15+16   : gate g (l15<8) / o (l15>=8)
        float gi[4], gf[4], gg[4], go[4];
#pragma unroll
        for (int r = 0; r < 4; ++r) {
            float a0 = acc0[r] + bias0;
            float a1 = acc1[r] + bias1;
            float p0 = __shfl_xor(a0, 8, 64);
            float p1 = __shfl_xor(a1, 8, 64);
            gi[r] = a0; gg[r] = a1; gf[r] = p0; go[r] = p1;
        }
        float hv[4];
        if (l15 < 8) {
#pragma unroll
            for (int r = 0; r < 4; ++r) {
                float iv = sigmoidf_(gi[r]);
                float fv = sigmoidf_(gf[r]);
                float gv = tanhf_(gg[r]);
                float ov = sigmoidf_(go[r]);
                cst[r] = fv * cst[r] + iv * gv;
                hv[r] = ov * tanhf_(cst[r]);
                // transpose through per-wave LDS patch (same-wave write->read)
                sH[w][(quad << 2) + r][l15] = f2bf(hv[r]);
            }
        }
        asm volatile("s_waitcnt lgkmcnt(0)" ::: "memory");
        // 16 lanes/wave publish this wave's 16 rows: coalesced 16 B each
        if (lane < 16) {
            uint4 v = *(const uint4*)&sH[w][lane][0];
            char* dst = hb_base + ((t & 1) << 16) + (blk << 10)
                        + (((w << 4) + lane) << 4);
            store_cg16(dst, v);
        }
        asm volatile("s_waitcnt vmcnt(0)" ::: "memory");  // h stores acked
        __syncthreads();
        if (tid == 0) {
            __hip_atomic_store(flags + (size_t)t * NB + blk, 1u,
                               __ATOMIC_RELAXED, __HIP_MEMORY_SCOPE_AGENT);
        }

        // ---- fp32 output stores: OFF the critical chain (retire during next poll) ----
        if (l15 < 8) {
            const int rbase = (w << 4) + (quad << 2);
            float* op = out + (size_t)t * (BATCH * HID) + hc0 + l15;
#pragma unroll
            for (int r = 0; r < 4; ++r)
                op[(size_t)(rbase + r) * HID] = hv[r];
        }
    }
}

extern "C" void kernel_launch(void* const* d_in, const int* in_sizes, int n_in,
                              void* d_out, int out_size, void* d_ws, size_t ws_size,
                              hipStream_t stream) {
    const float* x    = (const float*)d_in[0];
    const float* W_ih = (const float*)d_in[1];
    const float* W_hh = (const float*)d_in[2];
    const float* b_ih = (const float*)d_in[3];
    const float* b_hh = (const float*)d_in[4];
    float* out = (float*)d_out;

    unsigned int*   flags = (unsigned int*)d_ws;
    const size_t    flag_bytes = (size_t)T_STEPS * NB * sizeof(unsigned int);  // 128 KB
    unsigned short* hbuf  = (unsigned short*)((char*)d_ws + flag_bytes);        // 2x64 KB

    // flags re-zeroed every call (ws is re-poisoned to 0xAA by the harness)
    (void)hipMemsetAsync(flags, 0, flag_bytes, stream);

    hipLaunchKernelGGL(lstm_fused, dim3(NB), dim3(256), 0, stream,
                       x, W_ih, W_hh, b_ih, b_hh, out, flags, hbuf);
}

// Round 7
// 4297.530 us; speedup vs baseline: 1.5979x; 1.0054x over previous
//
#include <hip/hip_runtime.h>

// LSTM: T=512, B=64, I=512, H=512, gates 4H=2048. Inputs fp32, output fp32.
// One persistent kernel, 64 blocks x 256 threads (4 waves).
// Block b owns h-columns [8b, 8b+8) -> gate columns {q*512 + 8b + j}.
// W slices in LDS pre-swizzled (bf16) into MFMA B-fragment order.
// h published per-step as a COMPACT 1 KB/producer slice: [buf][p][row][8cols],
// coherent write-through 8B stores / coherent 8B loads.
// SYNC: per-step aggregated counter (global_atomic_add, 64B-padded) polled by
// ONE lane per block with s_sleep backoff — avoids the 4096-lane poll storm
// on shared flag lines that round-6 counters implicated.

#define T_STEPS 512
#define BATCH   64
#define HID     512
#define NB      64
#define CNT_STRIDE 16   // uints; 64 B between per-step counters

typedef short bf16x8 __attribute__((ext_vector_type(8)));
typedef float f32x4  __attribute__((ext_vector_type(4)));

struct U16B { unsigned long long x, y; };

__device__ __forceinline__ unsigned short f2bf(float f) {
    unsigned int u = __builtin_bit_cast(unsigned int, f);
    u += 0x7FFFu + ((u >> 16) & 1u);
    return (unsigned short)(u >> 16);
}
__device__ __forceinline__ unsigned int pack2(float lo, float hi) {
    return (unsigned int)f2bf(lo) | ((unsigned int)f2bf(hi) << 16);
}
// load 8 consecutive fp32 from p, round to bf16, pack into 16 B
__device__ __forceinline__ uint4 cvt8(const float* __restrict__ p) {
    float4 f0 = *(const float4*)p;
    float4 f1 = *(const float4*)(p + 4);
    uint4 r;
    r.x = pack2(f0.x, f0.y);
    r.y = pack2(f0.z, f0.w);
    r.z = pack2(f1.x, f1.y);
    r.w = pack2(f1.z, f1.w);
    return r;
}
// coherent (L2-bypassing) 16-byte h-fragment load as 2x8B relaxed agent atomics
__device__ __forceinline__ bf16x8 load_h16(const void* p) {
    const unsigned long long* q = (const unsigned long long*)p;
    U16B v;
    v.x = __hip_atomic_load(q,     __ATOMIC_RELAXED, __HIP_MEMORY_SCOPE_AGENT);
    v.y = __hip_atomic_load(q + 1, __ATOMIC_RELAXED, __HIP_MEMORY_SCOPE_AGENT);
    return __builtin_bit_cast(bf16x8, v);
}
// coherent write-through 16-byte store as 2x8B relaxed agent atomics
__device__ __forceinline__ void store_cg16(void* p, uint4 v) {
    unsigned long long* q = (unsigned long long*)p;
    U16B u = __builtin_bit_cast(U16B, v);
    __hip_atomic_store(q,     u.x, __ATOMIC_RELAXED, __HIP_MEMORY_SCOPE_AGENT);
    __hip_atomic_store(q + 1, u.y, __ATOMIC_RELAXED, __HIP_MEMORY_SCOPE_AGENT);
}
__device__ __forceinline__ float sigmoidf_(float x) {
    return 1.0f / (1.0f + __expf(-x));
}
__device__ __forceinline__ float tanhf_(float x) {
    x = fminf(fmaxf(x, -15.f), 15.f);
    float e = __expf(2.0f * x);
    return (e - 1.0f) / (e + 1.0f);
}

extern "C" __global__ void __launch_bounds__(256, 1)
lstm_fused(const float* __restrict__ x,
           const float* __restrict__ W_ih,
           const float* __restrict__ W_hh,
           const float* __restrict__ b_ih,
           const float* __restrict__ b_hh,
           float* __restrict__ out,
           unsigned int* __restrict__ cnt,      // [T_STEPS][CNT_STRIDE]
           unsigned short* __restrict__ hbuf)   // [2][NB][64 rows][8 cols] bf16
{
    // [matrix 0=W_ih,1=W_hh][ntile][kk][lane] : 16B per lane = MFMA B-fragment
    __shared__ uint4 sB[2][2][16][64];
    // per-wave h transpose patches
    __shared__ __align__(16) unsigned short sH[4][16][8];   // bf16 (h publish)
    __shared__ __align__(16) float          sHf[4][16][8];  // fp32 (out stores)

    const int blk  = blockIdx.x;
    const int tid  = threadIdx.x;
    const int w    = tid >> 6;    // wave id 0..3 -> M-tile (batch rows 16w..16w+15)
    const int lane = tid & 63;
    const int l15  = lane & 15;
    const int quad = lane >> 4;
    const int hc0  = blk * 8;     // first owned h-column

    // ---- one-time: stage W slices into LDS in B-fragment order (fp32 -> bf16) ----
    for (int u = tid; u < 2 * 16 * 64; u += 256) {
        int nt   = u >> 10;
        int kk   = (u >> 6) & 15;
        int ln   = u & 63;
        int c    = (ln & 15) + (nt << 4);                 // local gate col 0..31
        int grow = ((c >> 3) << 9) + hc0 + (c & 7);       // global W row (gate*512 + hcol)
        int k0   = kk * 32 + ((ln >> 4) << 3);
        sB[0][nt][kk][ln] = cvt8(W_ih + grow * 512 + k0);
        sB[1][nt][kk][ln] = cvt8(W_hh + grow * 512 + k0);
    }

    // per-lane biases for its two gate columns (fp32)
    float bias0, bias1;
    {
        int c0 = l15,      g0 = ((c0 >> 3) << 9) + hc0 + (c0 & 7);
        int c1 = l15 + 16, g1 = ((c1 >> 3) << 9) + hc0 + (c1 & 7);
        bias0 = b_ih[g0] + b_hh[g0];
        bias1 = b_ih[g1] + b_hh[g1];
    }
    __syncthreads();

    float cst[4] = {0.f, 0.f, 0.f, 0.f};     // c-state: 4 rows of owned column (lanes l15<8)
    const int aoff = (((w << 4) + l15) * 512) + (quad << 3);  // x A-fragment lane offset
    // consumer h-read base (row = 16w+l15, producer varies per chunk/quad)
    char* const hb_base = (char*)hbuf;
    const int   hread_off = (quad << 10) + (((w << 4) + l15) << 4);
    long long budget = 300000LL;              // deadlock safety valve (~poll iters)

    for (int t = 0; t < T_STEPS; ++t) {
        f32x4 acc0 = {0.f, 0.f, 0.f, 0.f};
        f32x4 acc1 = {0.f, 0.f, 0.f, 0.f};

        // ---- x-projection part (no cross-block dependency; hides wait) ----
        const float* xt = x + (size_t)t * (BATCH * 512) + aoff;
#pragma unroll
        for (int kk = 0; kk < 16; ++kk) {
            bf16x8 a  = __builtin_bit_cast(bf16x8, cvt8(xt + kk * 32));
            bf16x8 b0 = __builtin_bit_cast(bf16x8, sB[0][0][kk][lane]);
            bf16x8 b1 = __builtin_bit_cast(bf16x8, sB[0][1][kk][lane]);
            acc0 = __builtin_amdgcn_mfma_f32_16x16x32_bf16(a, b0, acc0, 0, 0, 0);
            acc1 = __builtin_amdgcn_mfma_f32_16x16x32_bf16(a, b1, acc1, 0, 0, 0);
        }

        // ---- recurrent part: wait for step t-1 counter, then accumulate ----
        if (t > 0) {
            if (tid == 0) {
                const unsigned int* cp = cnt + (size_t)(t - 1) * CNT_STRIDE;
                while (budget > 0) {
                    unsigned int v = __hip_atomic_load(cp, __ATOMIC_RELAXED,
                                                       __HIP_MEMORY_SCOPE_AGENT);
                    if (v >= NB) break;
                    __builtin_amdgcn_s_sleep(1);
                    --budget;
                }
            }
            __syncthreads();   // broadcast detection to all waves

            // chunk kk, quad q -> producer p = 4kk+q, 16 contiguous bytes at row
            const char* hp = hb_base + (((t - 1) & 1) << 16) + hread_off;
#pragma unroll
            for (int kk = 0; kk < 16; ++kk) {
                bf16x8 a  = load_h16(hp + (kk << 12));   // coherent L2-bypass load
                bf16x8 b0 = __builtin_bit_cast(bf16x8, sB[1][0][kk][lane]);
                bf16x8 b1 = __builtin_bit_cast(bf16x8, sB[1][1][kk][lane]);
                acc0 = __builtin_amdgcn_mfma_f32_16x16x32_bf16(a, b0, acc0, 0, 0, 0);
                acc1 = __builtin_amdgcn_mfma_f32_16x16x32_bf16(a, b1, acc1, 0, 0, 0);
            }
        }

        // ---- gates + state update ----
        // C-layout: col = lane&15, row = quad*4 + reg.
        // acc0 col c=l15      : gate i (l15<8) / f (l15>=8), h-col = hc0 + (l15&7)
        // acc1 col c=l15+16   : gate g (l15<8) / o (l15>=8)
        float gi[4], gf[4], gg[4], go[4];
#pragma unroll
        for (int r = 0; r < 4; ++r) {
            float a0 = acc0[r] + bias0;
            float a1 = acc1[r] + bias1;
            float p0 = __shfl_xor(a0, 8, 64);
            float p1 = __shfl_xor(a1, 8, 64);
            gi[r] = a0; gg[r] = a1; gf[r] = p0; go[r] = p1;
        }
        if (l15 < 8) {
#pragma unroll
            for (int r = 0; r < 4; ++r) {
                float iv = sigmoidf_(gi[r]);
                float fv = sigmoidf_(gf[r]);
                float gv = tanhf_(gg[r]);
                float ov = sigmoidf_(go[r]);
                cst[r] = fv * cst[r] + iv * gv;
                float hv = ov * tanhf_(cst[r]);
                // transpose through per-wave LDS patches (same-wave write->read)
                sH [w][(quad << 2) + r][l15] = f2bf(hv);
                sHf[w][(quad << 2) + r][l15] = hv;
            }
        }
        asm volatile("s_waitcnt lgkmcnt(0)" ::: "memory");
        // 16 lanes/wave publish this wave's 16 rows: coalesced 16 B each
        if (lane < 16) {
            uint4 v = *(const uint4*)&sH[w][lane][0];
            char* dst = hb_base + ((t & 1) << 16) + (blk << 10)
                        + (((w << 4) + lane) << 4);
            store_cg16(dst, v);
        }
        asm volatile("s_waitcnt vmcnt(0)" ::: "memory");  // h stores acked at IF
        __syncthreads();                                   // all waves acked
        if (tid == 0) {
            (void)__hip_atomic_fetch_add(cnt + (size_t)t * CNT_STRIDE, 1u,
                                         __ATOMIC_RELAXED, __HIP_MEMORY_SCOPE_AGENT);
        }

        // ---- fp32 output stores: coalesced, OFF the critical chain ----
        // wave w owns rows 16w..16w+15; its 8 cols are contiguous in each out row.
        if (lane < 32) {
            int row  = lane & 15;        // row within wave's M-tile
            int half = lane >> 4;        // which 16 B of the 32 B row-slice
            uint4 v = *(const uint4*)&sHf[w][row][half << 2];
            float* op = out + (size_t)t * (BATCH * HID)
                        + (size_t)((w << 4) + row) * HID + hc0 + (half << 2);
            *(uint4*)op = v;
        }
    }
}

extern "C" void kernel_launch(void* const* d_in, const int* in_sizes, int n_in,
                              void* d_out, int out_size, void* d_ws, size_t ws_size,
                              hipStream_t stream) {
    const float* x    = (const float*)d_in[0];
    const float* W_ih = (const float*)d_in[1];
    const float* W_hh = (const float*)d_in[2];
    const float* b_ih = (const float*)d_in[3];
    const float* b_hh = (const float*)d_in[4];
    float* out = (float*)d_out;

    unsigned int*   cnt = (unsigned int*)d_ws;
    const size_t    cnt_bytes = (size_t)T_STEPS * CNT_STRIDE * sizeof(unsigned int); // 32 KB
    unsigned short* hbuf = (unsigned short*)((char*)d_ws + cnt_bytes);               // 128 KB

    // counters re-zeroed every call (ws is re-poisoned to 0xAA by the harness)
    (void)hipMemsetAsync(cnt, 0, cnt_bytes, stream);

    hipLaunchKernelGGL(lstm_fused, dim3(NB), dim3(256), 0, stream,
                       x, W_ih, W_hh, b_ih, b_hh, out, cnt, hbuf);
}

// Round 8
// 3985.365 us; speedup vs baseline: 1.7230x; 1.0783x over previous
//
#include <hip/hip_runtime.h>

// LSTM: T=512, B=64, I=512, H=512, gates 4H=2048. Inputs fp32, output fp32.
// One persistent kernel, 64 blocks x 256 threads (4 waves).
// Block b owns h-columns [8b, 8b+8) -> gate columns {q*512 + 8b + j}.
// W slices in LDS pre-swizzled (bf16) into MFMA B-fragment order.
// h published per-step as a COMPACT 1 KB/producer slice: [buf][p][row][8cols],
// coherent write-through 8B stores / coherent 8B loads.
// SYNC: per-step aggregated counter polled by one lane per block.
// ROUND 8 CHANGE: h fragments are PRELOADED into registers in one unrolled
// batch (32 loads in flight together) before any MFMA consumes them —
// round 4-7 interleaved load->mfma serialized 16 coherence-point round trips.

#define T_STEPS 512
#define BATCH   64
#define HID     512
#define NB      64
#define CNT_STRIDE 16   // uints; 64 B between per-step counters

typedef short bf16x8 __attribute__((ext_vector_type(8)));
typedef float f32x4  __attribute__((ext_vector_type(4)));

struct U16B { unsigned long long x, y; };

__device__ __forceinline__ unsigned short f2bf(float f) {
    unsigned int u = __builtin_bit_cast(unsigned int, f);
    u += 0x7FFFu + ((u >> 16) & 1u);
    return (unsigned short)(u >> 16);
}
__device__ __forceinline__ unsigned int pack2(float lo, float hi) {
    return (unsigned int)f2bf(lo) | ((unsigned int)f2bf(hi) << 16);
}
// load 8 consecutive fp32 from p, round to bf16, pack into 16 B
__device__ __forceinline__ uint4 cvt8(const float* __restrict__ p) {
    float4 f0 = *(const float4*)p;
    float4 f1 = *(const float4*)(p + 4);
    uint4 r;
    r.x = pack2(f0.x, f0.y);
    r.y = pack2(f0.z, f0.w);
    r.z = pack2(f1.x, f1.y);
    r.w = pack2(f1.z, f1.w);
    return r;
}
// coherent write-through 16-byte store as 2x8B relaxed agent atomics
__device__ __forceinline__ void store_cg16(void* p, uint4 v) {
    unsigned long long* q = (unsigned long long*)p;
    U16B u = __builtin_bit_cast(U16B, v);
    __hip_atomic_store(q,     u.x, __ATOMIC_RELAXED, __HIP_MEMORY_SCOPE_AGENT);
    __hip_atomic_store(q + 1, u.y, __ATOMIC_RELAXED, __HIP_MEMORY_SCOPE_AGENT);
}
__device__ __forceinline__ float sigmoidf_(float x) {
    return 1.0f / (1.0f + __expf(-x));
}
__device__ __forceinline__ float tanhf_(float x) {
    x = fminf(fmaxf(x, -15.f), 15.f);
    float e = __expf(2.0f * x);
    return (e - 1.0f) / (e + 1.0f);
}

extern "C" __global__ void __launch_bounds__(256, 1)
lstm_fused(const float* __restrict__ x,
           const float* __restrict__ W_ih,
           const float* __restrict__ W_hh,
           const float* __restrict__ b_ih,
           const float* __restrict__ b_hh,
           float* __restrict__ out,
           unsigned int* __restrict__ cnt,      // [T_STEPS][CNT_STRIDE]
           unsigned short* __restrict__ hbuf)   // [2][NB][64 rows][8 cols] bf16
{
    // [matrix 0=W_ih,1=W_hh][ntile][kk][lane] : 16B per lane = MFMA B-fragment
    __shared__ uint4 sB[2][2][16][64];
    // per-wave h transpose patches
    __shared__ __align__(16) unsigned short sH[4][16][8];   // bf16 (h publish)
    __shared__ __align__(16) float          sHf[4][16][8];  // fp32 (out stores)

    const int blk  = blockIdx.x;
    const int tid  = threadIdx.x;
    const int w    = tid >> 6;    // wave id 0..3 -> M-tile (batch rows 16w..16w+15)
    const int lane = tid & 63;
    const int l15  = lane & 15;
    const int quad = lane >> 4;
    const int hc0  = blk * 8;     // first owned h-column

    // ---- one-time: stage W slices into LDS in B-fragment order (fp32 -> bf16) ----
    for (int u = tid; u < 2 * 16 * 64; u += 256) {
        int nt   = u >> 10;
        int kk   = (u >> 6) & 15;
        int ln   = u & 63;
        int c    = (ln & 15) + (nt << 4);                 // local gate col 0..31
        int grow = ((c >> 3) << 9) + hc0 + (c & 7);       // global W row (gate*512 + hcol)
        int k0   = kk * 32 + ((ln >> 4) << 3);
        sB[0][nt][kk][ln] = cvt8(W_ih + grow * 512 + k0);
        sB[1][nt][kk][ln] = cvt8(W_hh + grow * 512 + k0);
    }

    // per-lane biases for its two gate columns (fp32)
    float bias0, bias1;
    {
        int c0 = l15,      g0 = ((c0 >> 3) << 9) + hc0 + (c0 & 7);
        int c1 = l15 + 16, g1 = ((c1 >> 3) << 9) + hc0 + (c1 & 7);
        bias0 = b_ih[g0] + b_hh[g0];
        bias1 = b_ih[g1] + b_hh[g1];
    }
    __syncthreads();

    float cst[4] = {0.f, 0.f, 0.f, 0.f};     // c-state: 4 rows of owned column (lanes l15<8)
    const int aoff = (((w << 4) + l15) * 512) + (quad << 3);  // x A-fragment lane offset
    // consumer h-read base (row = 16w+l15, producer varies per chunk/quad)
    char* const hb_base = (char*)hbuf;
    const int   hread_off = (quad << 10) + (((w << 4) + l15) << 4);
    long long budget = 300000LL;              // deadlock safety valve (~poll iters)

    for (int t = 0; t < T_STEPS; ++t) {
        f32x4 acc0 = {0.f, 0.f, 0.f, 0.f};
        f32x4 acc1 = {0.f, 0.f, 0.f, 0.f};

        // ---- x-projection part (no cross-block dependency; hides producer skew) ----
        const float* xt = x + (size_t)t * (BATCH * 512) + aoff;
#pragma unroll
        for (int kk = 0; kk < 16; ++kk) {
            bf16x8 a  = __builtin_bit_cast(bf16x8, cvt8(xt + kk * 32));
            bf16x8 b0 = __builtin_bit_cast(bf16x8, sB[0][0][kk][lane]);
            bf16x8 b1 = __builtin_bit_cast(bf16x8, sB[0][1][kk][lane]);
            acc0 = __builtin_amdgcn_mfma_f32_16x16x32_bf16(a, b0, acc0, 0, 0, 0);
            acc1 = __builtin_amdgcn_mfma_f32_16x16x32_bf16(a, b1, acc1, 0, 0, 0);
        }

        // ---- recurrent part: wait for step t-1 counter, then accumulate ----
        if (t > 0) {
            if (tid == 0) {
                const unsigned int* cp = cnt + (size_t)(t - 1) * CNT_STRIDE;
                while (budget > 0) {
                    unsigned int v = __hip_atomic_load(cp, __ATOMIC_RELAXED,
                                                       __HIP_MEMORY_SCOPE_AGENT);
                    if (v >= NB) break;
                    __builtin_amdgcn_s_sleep(1);
                    --budget;
                }
            }
            __syncthreads();   // broadcast detection to all waves

            // PRELOAD all h fragments: 32 independent coherent 8B loads in flight
            const char* hp = hb_base + (((t - 1) & 1) << 16) + hread_off;
            U16B ha[16];
#pragma unroll
            for (int kk = 0; kk < 16; ++kk) {
                const unsigned long long* q =
                    (const unsigned long long*)(hp + (kk << 12));
                ha[kk].x = __hip_atomic_load(q,     __ATOMIC_RELAXED,
                                             __HIP_MEMORY_SCOPE_AGENT);
                ha[kk].y = __hip_atomic_load(q + 1, __ATOMIC_RELAXED,
                                             __HIP_MEMORY_SCOPE_AGENT);
            }
            // consume: backend pipelines vmcnt waits across the batch
#pragma unroll
            for (int kk = 0; kk < 16; ++kk) {
                bf16x8 a  = __builtin_bit_cast(bf16x8, ha[kk]);
                bf16x8 b0 = __builtin_bit_cast(bf16x8, sB[1][0][kk][lane]);
                bf16x8 b1 = __builtin_bit_cast(bf16x8, sB[1][1][kk][lane]);
                acc0 = __builtin_amdgcn_mfma_f32_16x16x32_bf16(a, b0, acc0, 0, 0, 0);
                acc1 = __builtin_amdgcn_mfma_f32_16x16x32_bf16(a, b1, acc1, 0, 0, 0);
            }
        }

        // ---- gates + state update ----
        // C-layout: col = lane&15, row = quad*4 + reg.
        // acc0 col c=l15      : gate i (l15<8) / f (l15>=8), h-col = hc0 + (l15&7)
        // acc1 col c=l15+16   : gate g (l15<8) / o (l15>=8)
        float gi[4], gf[4], gg[4], go[4];
#pragma unroll
        for (int r = 0; r < 4; ++r) {
            float a0 = acc0[r] + bias0;
            float a1 = acc1[r] + bias1;
            float p0 = __shfl_xor(a0, 8, 64);
            float p1 = __shfl_xor(a1, 8, 64);
            gi[r] = a0; gg[r] = a1; gf[r] = p0; go[r] = p1;
        }
        if (l15 < 8) {
#pragma unroll
            for (int r = 0; r < 4; ++r) {
                float iv = sigmoidf_(gi[r]);
                float fv = sigmoidf_(gf[r]);
                float gv = tanhf_(gg[r]);
                float ov = sigmoidf_(go[r]);
                cst[r] = fv * cst[r] + iv * gv;
                float hv = ov * tanhf_(cst[r]);
                // transpose through per-wave LDS patches (same-wave write->read)
                sH [w][(quad << 2) + r][l15] = f2bf(hv);
                sHf[w][(quad << 2) + r][l15] = hv;
            }
        }
        asm volatile("s_waitcnt lgkmcnt(0)" ::: "memory");
        // 16 lanes/wave publish this wave's 16 rows: coalesced 16 B each
        if (lane < 16) {
            uint4 v = *(const uint4*)&sH[w][lane][0];
            char* dst = hb_base + ((t & 1) << 16) + (blk << 10)
                        + (((w << 4) + lane) << 4);
            store_cg16(dst, v);
        }
        asm volatile("s_waitcnt vmcnt(0)" ::: "memory");  // h stores acked at IF
        __syncthreads();                                   // all waves acked
        if (tid == 0) {
            (void)__hip_atomic_fetch_add(cnt + (size_t)t * CNT_STRIDE, 1u,
                                         __ATOMIC_RELAXED, __HIP_MEMORY_SCOPE_AGENT);
        }

        // ---- fp32 output stores: coalesced, OFF the critical chain ----
        if (lane < 32) {
            int row  = lane & 15;        // row within wave's M-tile
            int half = lane >> 4;        // which 16 B of the 32 B row-slice
            uint4 v = *(const uint4*)&sHf[w][row][half << 2];
            float* op = out + (size_t)t * (BATCH * HID)
                        + (size_t)((w << 4) + row) * HID + hc0 + (half << 2);
            *(uint4*)op = v;
        }
    }
}

extern "C" void kernel_launch(void* const* d_in, const int* in_sizes, int n_in,
                              void* d_out, int out_size, void* d_ws, size_t ws_size,
                              hipStream_t stream) {
    const float* x    = (const float*)d_in[0];
    const float* W_ih = (const float*)d_in[1];
    const float* W_hh = (const float*)d_in[2];
    const float* b_ih = (const float*)d_in[3];
    const float* b_hh = (const float*)d_in[4];
    float* out = (float*)d_out;

    unsigned int*   cnt = (unsigned int*)d_ws;
    const size_t    cnt_bytes = (size_t)T_STEPS * CNT_STRIDE * sizeof(unsigned int); // 32 KB
    unsigned short* hbuf = (unsigned short*)((char*)d_ws + cnt_bytes);               // 128 KB

    // counters re-zeroed every call (ws is re-poisoned to 0xAA by the harness)
    (void)hipMemsetAsync(cnt, 0, cnt_bytes, stream);

    hipLaunchKernelGGL(lstm_fused, dim3(NB), dim3(256), 0, stream,
                       x, W_ih, W_hh, b_ih, b_hh, out, cnt, hbuf);
}